// Round 1
// baseline (356.410 us; speedup 1.0000x reference)
//
#include <hip/hip_runtime.h>

// Problem: GradientConsistencyLoss on f[2,3,192,192,192] fp32.
// loss = 0.1 * ( mean(div^2) + mean(sqrt(cx^2+cy^2+cz^2+1e-8)) )
// where grads use jnp.gradient semantics (central interior, one-sided edges).

#define DEP 192
#define HGT 192
#define WID 192
#define NB  2

constexpr int SD = HGT * WID;          // d-stride (floats)
constexpr int SC = DEP * SD;           // channel stride
constexpr int SB = 3 * SC;             // batch stride
constexpr int W4 = WID / 4;            // 48 float4-groups per row
constexpr int NG = NB * DEP * HGT * W4;  // 3,538,944 thread-groups
constexpr float SCALE = (float)(0.1 / (double)((long long)NB * DEP * HGT * WID));
constexpr float EPS_C = 1e-8f;

__global__ __launch_bounds__(256) void gcl_kernel(const float* __restrict__ f,
                                                  float* __restrict__ out) {
    const int g = blockIdx.x * 256 + threadIdx.x;

    // decompose g -> (b, d, h, w4); constant divisors -> magic-mul by compiler
    int w4 = g % W4;
    int t  = g / W4;
    int h  = t % HGT;
    t /= HGT;
    int d  = t % DEP;
    int b  = t / DEP;
    const int w = w4 * 4;

    // clamped neighbor indices + edge scale == jnp.gradient edge handling
    const int   dm = (d > 0) ? d - 1 : 0;
    const int   dp = (d < DEP - 1) ? d + 1 : DEP - 1;
    const float sx = (d == 0 || d == DEP - 1) ? 1.0f : 0.5f;
    const int   hm = (h > 0) ? h - 1 : 0;
    const int   hp = (h < HGT - 1) ? h + 1 : HGT - 1;
    const float sy = (h == 0 || h == HGT - 1) ? 1.0f : 0.5f;

    float dv[4] = {0.f, 0.f, 0.f, 0.f};
    float cx[4] = {0.f, 0.f, 0.f, 0.f};
    float cy[4] = {0.f, 0.f, 0.f, 0.f};
    float cz[4] = {0.f, 0.f, 0.f, 0.f};

    const int rowoff = h * WID + w;   // within (b,c,d) slab

#pragma unroll
    for (int c = 0; c < 3; ++c) {
        const float* fc = f + b * SB + c * SC;
        const float* pr = fc + d * SD + rowoff;

        const float4 v   = *(const float4*)pr;
        const float4 vdm = *(const float4*)(fc + dm * SD + rowoff);
        const float4 vdp = *(const float4*)(fc + dp * SD + rowoff);
        const float4 vhm = *(const float4*)(fc + d * SD + hm * WID + w);
        const float4 vhp = *(const float4*)(fc + d * SD + hp * WID + w);
        // w-neighbors across the float4 boundary (clamped addr, branchless)
        const float left  = pr[(w > 0) ? -1 : 0];
        const float right = pr[(w4 < W4 - 1) ? 4 : 3];

        const float vv[4]  = {v.x, v.y, v.z, v.w};
        const float vdm4[4] = {vdm.x, vdm.y, vdm.z, vdm.w};
        const float vdp4[4] = {vdp.x, vdp.y, vdp.z, vdp.w};
        const float vhm4[4] = {vhm.x, vhm.y, vhm.z, vhm.w};
        const float vhp4[4] = {vhp.x, vhp.y, vhp.z, vhp.w};

        float gx[4], gy[4], gz[4];
#pragma unroll
        for (int j = 0; j < 4; ++j) {
            gx[j] = sx * (vdp4[j] - vdm4[j]);
            gy[j] = sy * (vhp4[j] - vhm4[j]);
        }
        gz[0] = (w == 0)          ? (vv[1] - vv[0]) : 0.5f * (vv[1] - left);
        gz[1] = 0.5f * (vv[2] - vv[0]);
        gz[2] = 0.5f * (vv[3] - vv[1]);
        gz[3] = (w4 == W4 - 1)    ? (vv[3] - vv[2]) : 0.5f * (right - vv[2]);

#pragma unroll
        for (int j = 0; j < 4; ++j) {
            if (c == 0) { dv[j] += gx[j]; cz[j] += gy[j]; cy[j] -= gz[j]; }
            if (c == 1) { dv[j] += gy[j]; cx[j] += gz[j]; cz[j] -= gx[j]; }
            if (c == 2) { dv[j] += gz[j]; cx[j] -= gy[j]; cy[j] += gx[j]; }
        }
    }

    float local = 0.f;
#pragma unroll
    for (int j = 0; j < 4; ++j) {
        local += dv[j] * dv[j] +
                 sqrtf(cx[j] * cx[j] + cy[j] * cy[j] + cz[j] * cz[j] + EPS_C);
    }

    // wave64 butterfly -> cross-wave LDS -> one atomic per block
#pragma unroll
    for (int off = 32; off > 0; off >>= 1)
        local += __shfl_down(local, off, 64);

    __shared__ float wsum[4];
    const int lane = threadIdx.x & 63;
    const int wid  = threadIdx.x >> 6;
    if (lane == 0) wsum[wid] = local;
    __syncthreads();
    if (threadIdx.x == 0) {
        const float s = wsum[0] + wsum[1] + wsum[2] + wsum[3];
        atomicAdd(out, s * SCALE);
    }
}

extern "C" void kernel_launch(void* const* d_in, const int* in_sizes, int n_in,
                              void* d_out, int out_size, void* d_ws, size_t ws_size,
                              hipStream_t stream) {
    const float* f = (const float*)d_in[0];
    float* out = (float*)d_out;
    // d_out is re-poisoned to 0xAA before every timed launch -> zero it here.
    hipMemsetAsync(out, 0, sizeof(float), stream);
    gcl_kernel<<<dim3(NG / 256), dim3(256), 0, stream>>>(f, out);
}

// Round 2
// 254.797 us; speedup vs baseline: 1.3988x; 1.3988x over previous
//
#include <hip/hip_runtime.h>

// GradientConsistencyLoss on f[2,3,192,192,192] fp32.
// loss = 0.1 * ( mean(div^2) + mean(sqrt(cx^2+cy^2+cz^2+1e-8)) )
// jnp.gradient semantics: central interior, one-sided edges, unit spacing.
//
// R2: latency-bound fix. R1 had VGPR=36 -> compiler serialized the 21
// independent loads into ~7 dependent rounds (189us, 13% HBM, 15% VALU).
// Now: __launch_bounds__(256,4) for ~128 VGPR budget + all loads issued
// upfront + compiler barrier; atomics replaced by 2-stage reduction.

#define DEP 192
#define HGT 192
#define WID 192
#define NB  2

constexpr int SD = HGT * WID;            // d-stride (floats)
constexpr int SC = DEP * SD;             // channel stride
constexpr int SB = 3 * SC;               // batch stride
constexpr int W4 = WID / 4;              // 48 float4-groups per row
constexpr int NG   = NB * DEP * HGT * W4;   // 3,538,944 thread-groups
constexpr int NBLK = NG / 256;              // 13,824 blocks
constexpr float SCALE = (float)(0.1 / (double)((long long)NB * DEP * HGT * WID));
constexpr float EPS_C = 1e-8f;

__device__ __forceinline__ float4 ld4(const float* p) { return *(const float4*)p; }

__global__ __launch_bounds__(256, 4) void gcl_kernel(const float* __restrict__ f,
                                                     float* __restrict__ ws) {
    const int g = blockIdx.x * 256 + threadIdx.x;

    int w4 = g % W4;
    int t  = g / W4;
    int h  = t % HGT;
    t /= HGT;
    int d  = t % DEP;
    int b  = t / DEP;
    const int w = w4 * 4;

    const int   dm = (d > 0) ? d - 1 : 0;
    const int   dp = (d < DEP - 1) ? d + 1 : DEP - 1;
    const float sx = (d == 0 || d == DEP - 1) ? 1.0f : 0.5f;
    const int   hm = (h > 0) ? h - 1 : 0;
    const int   hp = (h < HGT - 1) ? h + 1 : HGT - 1;
    const float sy = (h == 0 || h == HGT - 1) ? 1.0f : 0.5f;

    const int rowoff = h * WID + w;
    const int loff = (w > 0) ? -1 : 0;          // left scalar offset (clamped)
    const int roff = (w4 < W4 - 1) ? 4 : 3;     // right scalar offset (clamped)

    const float* f0 = f + b * SB + 0 * SC;
    const float* f1 = f0 + SC;
    const float* f2 = f1 + SC;

    const float* p0 = f0 + d * SD + rowoff;
    const float* p1 = f1 + d * SD + rowoff;
    const float* p2 = f2 + d * SD + rowoff;

    // ---- issue ALL 21 independent loads before any consumption ----
    const float4 v0   = ld4(p0);
    const float4 v1   = ld4(p1);
    const float4 v2   = ld4(p2);
    const float4 vdm0 = ld4(f0 + dm * SD + rowoff);
    const float4 vdm1 = ld4(f1 + dm * SD + rowoff);
    const float4 vdm2 = ld4(f2 + dm * SD + rowoff);
    const float4 vdp0 = ld4(f0 + dp * SD + rowoff);
    const float4 vdp1 = ld4(f1 + dp * SD + rowoff);
    const float4 vdp2 = ld4(f2 + dp * SD + rowoff);
    const float4 vhm0 = ld4(f0 + d * SD + hm * WID + w);
    const float4 vhm1 = ld4(f1 + d * SD + hm * WID + w);
    const float4 vhm2 = ld4(f2 + d * SD + hm * WID + w);
    const float4 vhp0 = ld4(f0 + d * SD + hp * WID + w);
    const float4 vhp1 = ld4(f1 + d * SD + hp * WID + w);
    const float4 vhp2 = ld4(f2 + d * SD + hp * WID + w);
    const float  l0 = p0[loff], l1 = p1[loff], l2 = p2[loff];
    const float  r0 = p0[roff], r1 = p1[roff], r2 = p2[roff];
    asm volatile("" ::: "memory");   // keep loads clustered ahead of compute

    float dv[4], cx[4], cy[4], cz[4];

    const float vv0[4] = {v0.x, v0.y, v0.z, v0.w};
    const float vv1[4] = {v1.x, v1.y, v1.z, v1.w};
    const float vv2[4] = {v2.x, v2.y, v2.z, v2.w};

    // gx = sx*(f[dp]-f[dm]) ; gy = sy*(f[hp]-f[hm]) ; gz along w
    {
        const float a[4] = {vdp0.x - vdm0.x, vdp0.y - vdm0.y, vdp0.z - vdm0.z, vdp0.w - vdm0.w};
        const float bq[4] = {vhp0.x - vhm0.x, vhp0.y - vhm0.y, vhp0.z - vhm0.z, vhp0.w - vhm0.w};
        float gz[4];
        gz[0] = (w == 0)       ? (vv0[1] - vv0[0]) : 0.5f * (vv0[1] - l0);
        gz[1] = 0.5f * (vv0[2] - vv0[0]);
        gz[2] = 0.5f * (vv0[3] - vv0[1]);
        gz[3] = (w4 == W4 - 1) ? (vv0[3] - vv0[2]) : 0.5f * (r0 - vv0[2]);
#pragma unroll
        for (int j = 0; j < 4; ++j) {
            dv[j] = sx * a[j];             // gx of c0 -> div
            cz[j] = sy * bq[j];            // gy of c0 -> +cz
            cy[j] = -gz[j];                // gz of c0 -> -cy
        }
    }
    {
        const float a[4] = {vdp1.x - vdm1.x, vdp1.y - vdm1.y, vdp1.z - vdm1.z, vdp1.w - vdm1.w};
        const float bq[4] = {vhp1.x - vhm1.x, vhp1.y - vhm1.y, vhp1.z - vhm1.z, vhp1.w - vhm1.w};
        float gz[4];
        gz[0] = (w == 0)       ? (vv1[1] - vv1[0]) : 0.5f * (vv1[1] - l1);
        gz[1] = 0.5f * (vv1[2] - vv1[0]);
        gz[2] = 0.5f * (vv1[3] - vv1[1]);
        gz[3] = (w4 == W4 - 1) ? (vv1[3] - vv1[2]) : 0.5f * (r1 - vv1[2]);
#pragma unroll
        for (int j = 0; j < 4; ++j) {
            dv[j] += sy * bq[j];           // gy of c1 -> div
            cx[j]  = gz[j];                // gz of c1 -> +cx
            cz[j] -= sx * a[j];            // gx of c1 -> -cz
        }
    }
    {
        const float a[4] = {vdp2.x - vdm2.x, vdp2.y - vdm2.y, vdp2.z - vdm2.z, vdp2.w - vdm2.w};
        const float bq[4] = {vhp2.x - vhm2.x, vhp2.y - vhm2.y, vhp2.z - vhm2.z, vhp2.w - vhm2.w};
        float gz[4];
        gz[0] = (w == 0)       ? (vv2[1] - vv2[0]) : 0.5f * (vv2[1] - l2);
        gz[1] = 0.5f * (vv2[2] - vv2[0]);
        gz[2] = 0.5f * (vv2[3] - vv2[1]);
        gz[3] = (w4 == W4 - 1) ? (vv2[3] - vv2[2]) : 0.5f * (r2 - vv2[2]);
#pragma unroll
        for (int j = 0; j < 4; ++j) {
            dv[j] += gz[j];                // gz of c2 -> div
            cx[j] -= sy * bq[j];           // gy of c2 -> -cx
            cy[j] += sx * a[j];            // gx of c2 -> +cy
        }
    }

    float local = 0.f;
#pragma unroll
    for (int j = 0; j < 4; ++j) {
        local += dv[j] * dv[j] +
                 sqrtf(cx[j] * cx[j] + cy[j] * cy[j] + cz[j] * cz[j] + EPS_C);
    }

#pragma unroll
    for (int off = 32; off > 0; off >>= 1)
        local += __shfl_down(local, off, 64);

    __shared__ float wsum[4];
    const int lane = threadIdx.x & 63;
    const int wid  = threadIdx.x >> 6;
    if (lane == 0) wsum[wid] = local;
    __syncthreads();
    if (threadIdx.x == 0)
        ws[blockIdx.x] = wsum[0] + wsum[1] + wsum[2] + wsum[3];  // plain store, no atomic
}

__global__ __launch_bounds__(256) void gcl_reduce(const float* __restrict__ ws,
                                                  float* __restrict__ out) {
    float s = 0.f;
    for (int i = threadIdx.x; i < NBLK; i += 256) s += ws[i];
#pragma unroll
    for (int off = 32; off > 0; off >>= 1)
        s += __shfl_down(s, off, 64);
    __shared__ float wsum[4];
    const int lane = threadIdx.x & 63;
    const int wid  = threadIdx.x >> 6;
    if (lane == 0) wsum[wid] = s;
    __syncthreads();
    if (threadIdx.x == 0)
        out[0] = (wsum[0] + wsum[1] + wsum[2] + wsum[3]) * SCALE;
}

extern "C" void kernel_launch(void* const* d_in, const int* in_sizes, int n_in,
                              void* d_out, int out_size, void* d_ws, size_t ws_size,
                              hipStream_t stream) {
    const float* f = (const float*)d_in[0];
    float* out = (float*)d_out;
    float* ws  = (float*)d_ws;   // needs NBLK*4 = 55 KB of scratch
    gcl_kernel<<<dim3(NBLK), dim3(256), 0, stream>>>(f, ws);
    gcl_reduce<<<dim3(1), dim3(256), 0, stream>>>(ws, out);
}

// Round 3
// 240.379 us; speedup vs baseline: 1.4827x; 1.0600x over previous
//
#include <hip/hip_runtime.h>

// GradientConsistencyLoss on f[2,3,192,192,192] fp32.
// loss = 0.1 * ( mean(div^2) + mean(sqrt(cx^2+cy^2+cz^2+1e-8)) )
// jnp.gradient semantics: central interior, one-sided edges, unit spacing.
//
// R3: d-marching software pipeline. R2 (~88us kernel) was latency-bound:
// 21 loads -> one vmcnt(0) -> ~900cyc exposed per wave. Now each thread
// walks DSEG=8 planes; d+-1 centers roll through registers, and ALL loads
// for step s+1 (centers d+2, h+-1 rows at d+1, w-edge scalars) are issued
// one full iteration before their use. launch_bounds(256,3) -> ~170 VGPR
// budget for the pipeline state.

#define DEP 192
#define HGT 192
#define WID 192
#define NB  2

constexpr int SD = HGT * WID;            // d-stride (floats)
constexpr int SC = DEP * SD;             // channel stride
constexpr int SB = 3 * SC;               // batch stride
constexpr int W4 = WID / 4;              // 48 float4-groups per row
constexpr int DSEG = 8;                  // planes per thread
constexpr int NSEG = DEP / DSEG;         // 24 segments
constexpr int NG   = NB * NSEG * HGT * W4;  // 442,368 threads
constexpr int NBLK = NG / 256;              // 1,728 blocks
constexpr float SCALE = (float)(0.1 / (double)((long long)NB * DEP * HGT * WID));
constexpr float EPS_C = 1e-8f;

struct V4 { float v[4]; };
__device__ __forceinline__ V4 ld(const float* p) {
    const float4 t = *(const float4*)p;
    V4 r; r.v[0] = t.x; r.v[1] = t.y; r.v[2] = t.z; r.v[3] = t.w; return r;
}

__global__ __launch_bounds__(256, 3) void gcl_kernel(const float* __restrict__ f,
                                                     float* __restrict__ ws) {
    const int g = blockIdx.x * 256 + threadIdx.x;

    int w4 = g % W4;
    int t  = g / W4;
    int h  = t % HGT;
    t /= HGT;
    int ds = t % NSEG;
    int b  = t / NSEG;
    const int w  = w4 * 4;
    const int d0 = ds * DSEG;

    const int   hmi = (h > 0) ? h - 1 : 0;
    const int   hpi = (h < HGT - 1) ? h + 1 : HGT - 1;
    const float sy  = (h == 0 || h == HGT - 1) ? 1.0f : 0.5f;
    const int   dhm = (hmi - h) * WID;     // byte-free row offsets (floats)
    const int   dhp = (hpi - h) * WID;
    const int   loff = (w > 0) ? -1 : 0;
    const int   roff = (w4 < W4 - 1) ? 4 : 3;

    const float* base = f + b * SB + h * WID + w;

    // pipeline state (rolling registers)
    V4 prev[3], cur[3], nxt[3], vhm[3], vhp[3];
    float lf[3], rt[3];

    const int pm = (d0 > 0) ? d0 - 1 : 0;
#pragma unroll
    for (int c = 0; c < 3; ++c) {
        const float* pc = base + c * SC;
        prev[c] = ld(pc + pm * SD);
        cur[c]  = ld(pc + d0 * SD);
        nxt[c]  = ld(pc + (d0 + 1) * SD);   // d0+1 <= 185 < 192 always
        vhm[c]  = ld(pc + d0 * SD + dhm);
        vhp[c]  = ld(pc + d0 * SD + dhp);
        lf[c]   = (pc + d0 * SD)[loff];
        rt[c]   = (pc + d0 * SD)[roff];
    }

    float local = 0.f;

#pragma unroll
    for (int s = 0; s < DSEG; ++s) {
        const int d = d0 + s;

        // ---- prefetch everything for step s+1 (issued a full iter early) ----
        V4 nn[3], nhm[3], nhp[3];
        float nl[3], nr[3];
        if (s < DSEG - 1) {
            const int dn = d + 1;
            const int d2 = (d + 2 < DEP) ? d + 2 : DEP - 1;
#pragma unroll
            for (int c = 0; c < 3; ++c) {
                const float* pc = base + c * SC;
                nn[c]  = ld(pc + d2 * SD);
                nhm[c] = ld(pc + dn * SD + dhm);
                nhp[c] = ld(pc + dn * SD + dhp);
                nl[c]  = (pc + dn * SD)[loff];
                nr[c]  = (pc + dn * SD)[roff];
            }
        }

        // ---- compute plane d from data issued >= 1 iteration ago ----
        const float sx = (d == 0 || d == DEP - 1) ? 1.0f : 0.5f;
        float gx[3][4], gy[3][4], gz[3][4];
#pragma unroll
        for (int c = 0; c < 3; ++c) {
#pragma unroll
            for (int j = 0; j < 4; ++j) {
                gx[c][j] = sx * (nxt[c].v[j] - prev[c].v[j]);
                gy[c][j] = sy * (vhp[c].v[j] - vhm[c].v[j]);
            }
            gz[c][0] = (w == 0)       ? (cur[c].v[1] - cur[c].v[0])
                                      : 0.5f * (cur[c].v[1] - lf[c]);
            gz[c][1] = 0.5f * (cur[c].v[2] - cur[c].v[0]);
            gz[c][2] = 0.5f * (cur[c].v[3] - cur[c].v[1]);
            gz[c][3] = (w4 == W4 - 1) ? (cur[c].v[3] - cur[c].v[2])
                                      : 0.5f * (rt[c] - cur[c].v[2]);
        }
#pragma unroll
        for (int j = 0; j < 4; ++j) {
            const float dv = gx[0][j] + gy[1][j] + gz[2][j];
            const float cx = gz[1][j] - gy[2][j];
            const float cy = gx[2][j] - gz[0][j];
            const float cz = gy[0][j] - gx[1][j];
            local += dv * dv + sqrtf(cx * cx + cy * cy + cz * cz + EPS_C);
        }

        // ---- rotate pipeline ----
        if (s < DSEG - 1) {
#pragma unroll
            for (int c = 0; c < 3; ++c) {
                prev[c] = cur[c]; cur[c] = nxt[c]; nxt[c] = nn[c];
                vhm[c] = nhm[c]; vhp[c] = nhp[c];
                lf[c] = nl[c];   rt[c] = nr[c];
            }
        }
    }

    // wave64 butterfly -> cross-wave LDS -> one store per block
#pragma unroll
    for (int off = 32; off > 0; off >>= 1)
        local += __shfl_down(local, off, 64);

    __shared__ float wsum[4];
    const int lane = threadIdx.x & 63;
    const int wv   = threadIdx.x >> 6;
    if (lane == 0) wsum[wv] = local;
    __syncthreads();
    if (threadIdx.x == 0)
        ws[blockIdx.x] = wsum[0] + wsum[1] + wsum[2] + wsum[3];
}

__global__ __launch_bounds__(256) void gcl_reduce(const float* __restrict__ ws,
                                                  float* __restrict__ out) {
    float s = 0.f;
    for (int i = threadIdx.x; i < NBLK; i += 256) s += ws[i];
#pragma unroll
    for (int off = 32; off > 0; off >>= 1)
        s += __shfl_down(s, off, 64);
    __shared__ float wsum[4];
    const int lane = threadIdx.x & 63;
    const int wv   = threadIdx.x >> 6;
    if (lane == 0) wsum[wv] = s;
    __syncthreads();
    if (threadIdx.x == 0)
        out[0] = (wsum[0] + wsum[1] + wsum[2] + wsum[3]) * SCALE;
}

extern "C" void kernel_launch(void* const* d_in, const int* in_sizes, int n_in,
                              void* d_out, int out_size, void* d_ws, size_t ws_size,
                              hipStream_t stream) {
    const float* f = (const float*)d_in[0];
    float* out = (float*)d_out;
    float* ws  = (float*)d_ws;   // NBLK*4 = 6.75 KB of scratch
    gcl_kernel<<<dim3(NBLK), dim3(256), 0, stream>>>(f, ws);
    gcl_reduce<<<dim3(1), dim3(256), 0, stream>>>(ws, out);
}